// Round 3
// baseline (1717.999 us; speedup 1.0000x reference)
//
#include <hip/hip_runtime.h>
#include <math.h>

#define B_ 256
#define T_ 512
#define D_ 128
#define H_ 64

// ---------------- persistent workspace layout (floats) ----------------
// sf    : [T][B][64]  HB-forward outputs
// sb    : [T][B][64]  HB-backward outputs (stored at forward time index)
// state : 7 x [B][64] (gru h | hbf h,k,kp | hbb h,k,kp)
// fastl : [B][128]    fast_last
// logit : [B][512]    attention logits -> softmax weights (in-place)
// ctx   : [B][128]    stable_ctx
// chunk : xg_c [C][B][192], xpf_c [C][B][320], xpb_c [C][B][320]
static const size_t F_SF    = 0;
static const size_t F_SB    = F_SF + (size_t)T_ * B_ * 64;
static const size_t F_ST    = F_SB + (size_t)T_ * B_ * 64;
static const size_t F_FASTL = F_ST + (size_t)7 * B_ * 64;
static const size_t F_LOG   = F_FASTL + (size_t)B_ * 128;
static const size_t F_CTX   = F_LOG + (size_t)B_ * T_;
static const size_t F_CHUNK = F_CTX + (size_t)B_ * 128;   // ~17.1M floats persistent

__device__ __forceinline__ float sigmoidf_(float x) {
    return 1.0f / (1.0f + __expf(-x));
}
__device__ __forceinline__ float tanhf_(float x) {
    float ax = fabsf(x);
    float e  = __expf(-2.0f * ax);
    float t  = (1.0f - e) / (1.0f + e);
    return copysignf(t, x);
}
__device__ __forceinline__ float wave_sum(float v) {
#pragma unroll
    for (int off = 32; off > 0; off >>= 1) v += __shfl_xor(v, off);
    return v;
}
__device__ __forceinline__ float wave_max(float v) {
#pragma unroll
    for (int off = 32; off > 0; off >>= 1) v = fmaxf(v, __shfl_xor(v, off));
    return v;
}

// ---------------------------------------------------------------------------
// Input GEMM over a chunk of C timesteps (grid.z = C, chunk-local).
// out[(tl*B + b)][g] = sum_d x[b][txi][d] * W(g,d) + b1[g] (+ b2[g])
// WGD=true : W is [G][D] (GRU Wi);  WGD=false: W is [D][G] (HB W)
// REV=true : txi = T-1-(t0+tl)
// ---------------------------------------------------------------------------
template<int N, bool WGD, bool REV>
__global__ __launch_bounds__(256) void gemm_in(
    const float* __restrict__ x, const float* __restrict__ W,
    const float* __restrict__ b1, const float* __restrict__ b2,
    float* __restrict__ out, int t0)
{
    __shared__ float a_lds[64 * 68];   // [k_local][m] padded
    __shared__ float w_lds[64 * 68];   // [k_local][n] padded

    const int tid = threadIdx.x;
    const int tl  = blockIdx.z;
    const int tg  = t0 + tl;
    const int txi = REV ? (T_ - 1 - tg) : tg;
    const int b0  = blockIdx.y * 64;
    const int g0  = blockIdx.x * 64;

    const int ty = tid >> 4, tx = tid & 15;
    float acc[4][4] = {};

    for (int kh = 0; kh < 2; kh++) {
#pragma unroll
        for (int i = 0; i < 4; i++) {
            int flat = i * 256 + tid;        // 0..1023
            int r  = flat >> 4;              // 0..63 (m)
            int c4 = flat & 15;              // 0..15 (k quad)
            const float4 v = *reinterpret_cast<const float4*>(
                x + ((size_t)(b0 + r) * T_ + txi) * D_ + kh * 64 + c4 * 4);
            a_lds[(c4 * 4 + 0) * 68 + r] = v.x;
            a_lds[(c4 * 4 + 1) * 68 + r] = v.y;
            a_lds[(c4 * 4 + 2) * 68 + r] = v.z;
            a_lds[(c4 * 4 + 3) * 68 + r] = v.w;
        }
        if (WGD) {
#pragma unroll
            for (int i = 0; i < 4; i++) {
                int flat = i * 256 + tid;
                int r  = flat >> 4;          // n
                int c4 = flat & 15;          // k quad
                const float4 v = *reinterpret_cast<const float4*>(
                    W + (size_t)(g0 + r) * D_ + kh * 64 + c4 * 4);
                w_lds[(c4 * 4 + 0) * 68 + r] = v.x;
                w_lds[(c4 * 4 + 1) * 68 + r] = v.y;
                w_lds[(c4 * 4 + 2) * 68 + r] = v.z;
                w_lds[(c4 * 4 + 3) * 68 + r] = v.w;
            }
        } else {
#pragma unroll
            for (int i = 0; i < 4; i++) {
                int flat = i * 256 + tid;
                int k  = flat >> 4;          // k_local
                int c4 = flat & 15;          // n quad
                const float4 v = *reinterpret_cast<const float4*>(
                    W + (size_t)(kh * 64 + k) * N + g0 + c4 * 4);
                *reinterpret_cast<float4*>(&w_lds[k * 68 + c4 * 4]) = v;
            }
        }
        __syncthreads();
#pragma unroll 8
        for (int k = 0; k < 64; k++) {
            const float4 av = *reinterpret_cast<const float4*>(&a_lds[k * 68 + ty * 4]);
            const float4 wv = *reinterpret_cast<const float4*>(&w_lds[k * 68 + tx * 4]);
            const float am[4] = {av.x, av.y, av.z, av.w};
            const float wn[4] = {wv.x, wv.y, wv.z, wv.w};
#pragma unroll
            for (int mi = 0; mi < 4; mi++)
#pragma unroll
                for (int ni = 0; ni < 4; ni++)
                    acc[mi][ni] = fmaf(am[mi], wn[ni], acc[mi][ni]);
        }
        __syncthreads();
    }

    float bias[4];
#pragma unroll
    for (int ni = 0; ni < 4; ni++) {
        float bb = b1[g0 + tx * 4 + ni];
        if (b2 != nullptr) bb += b2[g0 + tx * 4 + ni];
        bias[ni] = bb;
    }
#pragma unroll
    for (int mi = 0; mi < 4; mi++) {
        float4 o;
        o.x = acc[mi][0] + bias[0];
        o.y = acc[mi][1] + bias[1];
        o.z = acc[mi][2] + bias[2];
        o.w = acc[mi][3] + bias[3];
        *reinterpret_cast<float4*>(
            out + ((size_t)tl * B_ + b0 + ty * 4 + mi) * N + g0 + tx * 4) = o;
    }
}

// ---------------------------------------------------------------------------
// All sequential recurrences for one time-chunk [t0, t0+C).
// blocks 0..63   : GRU forward  (4 batch/block, state h)
// blocks 64..127 : HB forward   (4 batch/block, full sequence out, state h,k,kp)
// blocks 128..191: HB backward
// wave = batch slot, lane w = hidden index. Lane owns gates {w, w+64,...} ->
// update is thread-local; h broadcast via per-wave LDS row (no barrier needed:
// same-wave DS ops are program-ordered and may-alias -> compiler keeps order).
// Recurrent weights held in VGPRs (launch_bounds(256,1) -> 512-VGPR budget).
// ---------------------------------------------------------------------------
__global__ __launch_bounds__(256, 1) void recur(
    const float* __restrict__ xg_c, const float* __restrict__ xpf_c,
    const float* __restrict__ xpb_c,
    const float* __restrict__ gWh, const float* __restrict__ gbh,
    const float* __restrict__ Uf,  const float* __restrict__ Ub,
    float* __restrict__ sf, float* __restrict__ sb,
    float* __restrict__ state, int t0, int C)
{
    __shared__ float h_lds[4][64];
    const int tid = threadIdx.x;
    const int w   = tid & 63;
    const int wb  = tid >> 6;   // wave index = batch slot

    if (blockIdx.x < 64) {
        // ---------------- GRU forward ----------------
        const int batch = blockIdx.x * 4 + wb;
        float* stH = state;  // offset 0
        float h = (t0 == 0) ? 0.0f : stH[(size_t)batch * 64 + w];
        h_lds[wb][w] = h;

        float wh[3][64];
        float bh3[3];
#pragma unroll
        for (int gi = 0; gi < 3; gi++) {
            bh3[gi] = gbh[gi * 64 + w];
#pragma unroll
            for (int j = 0; j < 64; j++)
                wh[gi][j] = gWh[(size_t)(gi * 64 + w) * 64 + j];
        }
        float xv[3];
        {
            const float* p = xg_c + (size_t)batch * 192;
            xv[0] = p[w]; xv[1] = p[64 + w]; xv[2] = p[128 + w];
        }
        for (int t = 0; t < C; t++) {
            float xn0, xn1, xn2;
            {
                int tn = (t + 1 < C) ? (t + 1) : t;
                const float* pn = xg_c + ((size_t)tn * B_ + batch) * 192;
                xn0 = pn[w]; xn1 = pn[64 + w]; xn2 = pn[128 + w];
            }
            float a0 = bh3[0], a1 = bh3[1], a2 = bh3[2];
#pragma unroll
            for (int j4 = 0; j4 < 16; j4++) {
                const float4 hv = *reinterpret_cast<const float4*>(&h_lds[wb][j4 * 4]);
                const float hq[4] = {hv.x, hv.y, hv.z, hv.w};
#pragma unroll
                for (int q = 0; q < 4; q++) {
                    a0 = fmaf(hq[q], wh[0][j4 * 4 + q], a0);
                    a1 = fmaf(hq[q], wh[1][j4 * 4 + q], a1);
                    a2 = fmaf(hq[q], wh[2][j4 * 4 + q], a2);
                }
            }
            float r = sigmoidf_(xv[0] + a0);
            float z = sigmoidf_(xv[1] + a1);
            float n = tanhf_(xv[2] + r * a2);
            h = (1.0f - z) * n + z * h;
            h_lds[wb][w] = h;
            xv[0] = xn0; xv[1] = xn1; xv[2] = xn2;
        }
        stH[(size_t)batch * 64 + w] = h;
    } else {
        // ---------------- Hierarchical block (f / b) ----------------
        const int idx   = blockIdx.x - 64;
        const int dir   = idx >> 6;                 // 0 fwd, 1 bwd
        const int batch = (idx & 63) * 4 + wb;
        const float* U  = dir ? Ub : Uf;
        const float* xp = dir ? xpb_c : xpf_c;
        float* outbuf   = dir ? sb : sf;
        float* stH  = state + (size_t)(1 + dir * 3) * B_ * 64;
        float* stK  = stH + (size_t)B_ * 64;
        float* stKp = stK + (size_t)B_ * 64;

        float h, k, kp;
        if (t0 == 0) { h = 0.0f; k = 0.0f; kp = 0.0f; }
        else {
            h  = stH [(size_t)batch * 64 + w];
            k  = stK [(size_t)batch * 64 + w];
            kp = stKp[(size_t)batch * 64 + w];
        }
        h_lds[wb][w] = h;

        float u[5][64];
#pragma unroll
        for (int j = 0; j < 64; j++)
#pragma unroll
            for (int gq = 0; gq < 5; gq++)
                u[gq][j] = U[(size_t)j * 320 + gq * 64 + w];

        float xv[5];
        {
            const float* p = xp + (size_t)batch * 320;
#pragma unroll
            for (int gq = 0; gq < 5; gq++) xv[gq] = p[gq * 64 + w];
        }
        for (int t = 0; t < C; t++) {
            float xn[5];
            {
                int tn = (t + 1 < C) ? (t + 1) : t;
                const float* pn = xp + ((size_t)tn * B_ + batch) * 320;
#pragma unroll
                for (int gq = 0; gq < 5; gq++) xn[gq] = pn[gq * 64 + w];
            }
            float a0 = 0.f, a1 = 0.f, a2 = 0.f, a3 = 0.f, a4 = 0.f;
#pragma unroll
            for (int j4 = 0; j4 < 16; j4++) {
                const float4 hv = *reinterpret_cast<const float4*>(&h_lds[wb][j4 * 4]);
                const float hq[4] = {hv.x, hv.y, hv.z, hv.w};
#pragma unroll
                for (int q = 0; q < 4; q++) {
                    a0 = fmaf(hq[q], u[0][j4 * 4 + q], a0);
                    a1 = fmaf(hq[q], u[1][j4 * 4 + q], a1);
                    a2 = fmaf(hq[q], u[2][j4 * 4 + q], a2);
                    a3 = fmaf(hq[q], u[3][j4 * 4 + q], a3);
                    a4 = fmaf(hq[q], u[4][j4 * 4 + q], a4);
                }
            }
            float f   = sigmoidf_(xv[0] + a0);
            float ii  = sigmoidf_(xv[1] + a1);
            float o   = sigmoidf_(xv[2] + a2);
            float uu  = sigmoidf_(xv[3] + a3);
            float tkc = tanhf_(xv[4] + a4);
            kp = uu * tkc + (1.0f - uu) * kp;
            k  = f * k + ii * kp;
            h  = o * tanhf_(k);
            int tg   = t0 + t;
            int tout = dir ? (T_ - 1 - tg) : tg;
            outbuf[((size_t)tout * B_ + batch) * 64 + w] = h;
            h_lds[wb][w] = h;
#pragma unroll
            for (int gq = 0; gq < 5; gq++) xv[gq] = xn[gq];
        }
        stH [(size_t)batch * 64 + w] = h;
        stK [(size_t)batch * 64 + w] = k;
        stKp[(size_t)batch * 64 + w] = kp;
    }
}

// ---------------------------------------------------------------------------
// tail1: backward-GRU single step (hb_[0], h0=0 => hg = bh) + fast_last proj.
// One block (64 lanes) per batch element.
// ---------------------------------------------------------------------------
__global__ __launch_bounds__(64) void tail1(
    const float* __restrict__ x, const float* __restrict__ Wib,
    const float* __restrict__ bib, const float* __restrict__ bhb,
    const float* __restrict__ hfl, const float* __restrict__ fW,
    const float* __restrict__ fb, float* __restrict__ fastl)
{
    __shared__ float xrow[128];
    __shared__ float inb[128];
    const int b = blockIdx.x;
    const int l = threadIdx.x;
    xrow[l]      = x[((size_t)b * T_ + (T_ - 1)) * D_ + l];
    xrow[64 + l] = x[((size_t)b * T_ + (T_ - 1)) * D_ + 64 + l];
    inb[l] = hfl[(size_t)b * 64 + l];
    __syncthreads();
    float a0 = bib[l], a1 = bib[64 + l], a2 = bib[128 + l];
#pragma unroll 8
    for (int d = 0; d < 128; d++) {
        float xd = xrow[d];
        a0 = fmaf(xd, Wib[(size_t)l * 128 + d], a0);
        a1 = fmaf(xd, Wib[(size_t)(64 + l) * 128 + d], a1);
        a2 = fmaf(xd, Wib[(size_t)(128 + l) * 128 + d], a2);
    }
    float r = sigmoidf_(a0 + bhb[l]);
    float z = sigmoidf_(a1 + bhb[64 + l]);
    float n = tanhf_(a2 + r * bhb[128 + l]);
    inb[64 + l] = (1.0f - z) * n;
    __syncthreads();
    float acc0 = fb[l], acc1 = fb[64 + l];
#pragma unroll 8
    for (int i2 = 0; i2 < 128; i2++) {
        float v = inb[i2];
        acc0 = fmaf(v, fW[(size_t)i2 * 128 + l], acc0);
        acc1 = fmaf(v, fW[(size_t)i2 * 128 + 64 + l], acc1);
    }
    fastl[(size_t)b * 128 + l]      = acc0;
    fastl[(size_t)b * 128 + 64 + l] = acc1;
}

// ---------------------------------------------------------------------------
// Fused attention logits: logits[b,t] = tanh(stable@Wp + bp) @ Ws + bs
// One wave per (b,t); Wp cached transposed in LDS.
// ---------------------------------------------------------------------------
__global__ __launch_bounds__(256) void attn_logits(
    const float* __restrict__ sf, const float* __restrict__ sb,
    const float* __restrict__ Wp, const float* __restrict__ bp,
    const float* __restrict__ Ws, const float* __restrict__ bs,
    float* __restrict__ logits)
{
    __shared__ float wp_t[64 * 129];
    __shared__ float s_lds[4][132];
    __shared__ float bp_l[64], ws_l[64];
    const int tid = threadIdx.x;
#pragma unroll
    for (int i = 0; i < 32; i++) {
        int idx = i * 256 + tid;        // 8192 = 128*64
        int d = idx >> 6, g = idx & 63;
        wp_t[g * 129 + d] = Wp[idx];
    }
    if (tid < 64) { bp_l[tid] = bp[tid]; ws_l[tid] = Ws[tid]; }
    __syncthreads();
    const int wave = tid >> 6, l = tid & 63;
    for (int it = 0; it < 64; it++) {
        int p  = blockIdx.x * 256 + wave * 64 + it;
        int bb = p >> 9;
        int t  = p & 511;
        s_lds[wave][l]      = sf[((size_t)t * B_ + bb) * 64 + l];
        s_lds[wave][64 + l] = sb[((size_t)t * B_ + bb) * 64 + l];
        float acc = bp_l[l];
#pragma unroll 8
        for (int d = 0; d < 128; d++)
            acc = fmaf(s_lds[wave][d], wp_t[l * 129 + d], acc);
        float v = tanhf_(acc) * ws_l[l];
        v = wave_sum(v);
        if (l == 0) logits[(size_t)bb * T_ + t] = v + bs[0];
    }
}

__global__ __launch_bounds__(256) void softmax_k(float* __restrict__ logits)
{
    __shared__ float red[8];
    const int b = blockIdx.x, tid = threadIdx.x;
    const int wave = tid >> 6, l = tid & 63;
    float* row = logits + (size_t)b * T_;
    float l0 = row[tid], l1 = row[tid + 256];
    float m = wave_max(fmaxf(l0, l1));
    if (l == 0) red[wave] = m;
    __syncthreads();
    m = fmaxf(fmaxf(red[0], red[1]), fmaxf(red[2], red[3]));
    float e0 = __expf(l0 - m), e1 = __expf(l1 - m);
    float s = wave_sum(e0 + e1);
    if (l == 0) red[4 + wave] = s;
    __syncthreads();
    s = red[4] + red[5] + red[6] + red[7];
    row[tid]       = e0 / s;
    row[tid + 256] = e1 / s;
}

// stable_ctx = (sum_t w[b,t]*stable[b,t,:]) @ stab_W + stab_b
__global__ __launch_bounds__(128) void ctx_k(
    const float* __restrict__ wsm, const float* __restrict__ sf,
    const float* __restrict__ sb, const float* __restrict__ stW,
    const float* __restrict__ stb, float* __restrict__ ctxo)
{
    __shared__ float wrow[512];
    __shared__ float cpre[128];
    const int b = blockIdx.x, tid = threadIdx.x;
#pragma unroll
    for (int i = 0; i < 4; i++) wrow[i * 128 + tid] = wsm[(size_t)b * T_ + i * 128 + tid];
    __syncthreads();
    const float* src = (tid < 64) ? sf : sb;
    const int d = tid & 63;
    float acc = 0.0f;
#pragma unroll 4
    for (int t = 0; t < 512; t++)
        acc = fmaf(wrow[t], src[((size_t)t * B_ + b) * 64 + d], acc);
    cpre[tid] = acc;
    __syncthreads();
    float a2 = stb[tid];
#pragma unroll 8
    for (int i2 = 0; i2 < 128; i2++)
        a2 = fmaf(cpre[i2], stW[(size_t)i2 * 128 + tid], a2);
    ctxo[(size_t)b * 128 + tid] = a2;
}

// gate MLP + fused + head MLP -> d_out[b]
__global__ __launch_bounds__(128) void tail2(
    const float* __restrict__ fastl, const float* __restrict__ ctxo,
    const float* __restrict__ gW1, const float* __restrict__ gb1,
    const float* __restrict__ gW2, const float* __restrict__ gb2,
    const float* __restrict__ hW1, const float* __restrict__ hb1,
    const float* __restrict__ hW2, const float* __restrict__ hb2,
    float* __restrict__ outp)
{
    __shared__ float gin[256];
    __shared__ float outv[384];
    __shared__ float red2[2];
    const int b = blockIdx.x, tid = threadIdx.x;
    gin[tid]       = fastl[(size_t)b * 128 + tid];
    gin[128 + tid] = ctxo[(size_t)b * 128 + tid];
    __syncthreads();
    float a = gb1[tid];
#pragma unroll 8
    for (int i = 0; i < 256; i++)
        a = fmaf(gin[i], gW1[(size_t)i * 128 + tid], a);
    float gh = fmaxf(a, 0.0f);
    float v = wave_sum(gh * gW2[tid]);
    if ((tid & 63) == 0) red2[tid >> 6] = v;
    __syncthreads();
    float gate = sigmoidf_(red2[0] + red2[1] + gb2[0]);
    float fl = gin[tid], sc = gin[128 + tid];
    outv[tid]       = gate * fl + (1.0f - gate) * sc;
    outv[128 + tid] = fl;
    outv[256 + tid] = sc;
    __syncthreads();
    float a1 = hb1[tid];
#pragma unroll 8
    for (int i = 0; i < 384; i++)
        a1 = fmaf(outv[i], hW1[(size_t)i * 128 + tid], a1);
    float h1v = fmaxf(a1, 0.0f);
    float vv = wave_sum(h1v * hW2[tid]);
    if ((tid & 63) == 0) red2[tid >> 6] = vv;
    __syncthreads();
    if (tid == 0) outp[b] = red2[0] + red2[1] + hb2[0];
}

extern "C" void kernel_launch(void* const* d_in, const int* in_sizes, int n_in,
                              void* d_out, int out_size, void* d_ws, size_t ws_size,
                              hipStream_t stream)
{
    (void)in_sizes; (void)n_in; (void)out_size;
    const float* x      = (const float*)d_in[0];
    const float* gfWi   = (const float*)d_in[1];
    const float* gfWh   = (const float*)d_in[2];
    const float* gfbi   = (const float*)d_in[3];
    const float* gfbh   = (const float*)d_in[4];
    const float* gbWi   = (const float*)d_in[5];
    // d_in[6] = gru_b_Wh (unused: backward GRU contributes only its first step)
    const float* gbbi   = (const float*)d_in[7];
    const float* gbbh   = (const float*)d_in[8];
    const float* hbfW   = (const float*)d_in[9];
    const float* hbfb   = (const float*)d_in[10];
    const float* hbfU   = (const float*)d_in[11];
    const float* hbfc   = (const float*)d_in[12];
    const float* hbbW   = (const float*)d_in[13];
    const float* hbbb   = (const float*)d_in[14];
    const float* hbbU   = (const float*)d_in[15];
    const float* hbbc   = (const float*)d_in[16];
    const float* fastW  = (const float*)d_in[17];
    const float* fastb  = (const float*)d_in[18];
    const float* stabW  = (const float*)d_in[19];
    const float* stabb  = (const float*)d_in[20];
    const float* attnpW = (const float*)d_in[21];
    const float* attnpb = (const float*)d_in[22];
    const float* attnsW = (const float*)d_in[23];
    const float* attnsb = (const float*)d_in[24];
    const float* gW1    = (const float*)d_in[25];
    const float* gb1    = (const float*)d_in[26];
    const float* gW2    = (const float*)d_in[27];
    const float* gb2    = (const float*)d_in[28];
    const float* hW1    = (const float*)d_in[29];
    const float* hb1    = (const float*)d_in[30];
    const float* hW2    = (const float*)d_in[31];
    const float* hb2    = (const float*)d_in[32];

    float* ws    = (float*)d_ws;
    float* sf    = ws + F_SF;
    float* sb    = ws + F_SB;
    float* st    = ws + F_ST;
    float* fastl = ws + F_FASTL;
    float* logit = ws + F_LOG;
    float* ctxo  = ws + F_CTX;

    // Adaptive chunk size from ws_size (deterministic per run -> graph-safe).
    // Chunk needs C*B*(192+320+320) = C*212992 floats beyond F_CHUNK.
    const size_t wsf = ws_size / sizeof(float);
    int C = T_;
    while (C > 1 && F_CHUNK + (size_t)C * B_ * 832 > wsf) C >>= 1;
    const int nc = T_ / C;

    float* xg_c  = ws + F_CHUNK;
    float* xpf_c = xg_c  + (size_t)C * B_ * 192;
    float* xpb_c = xpf_c + (size_t)C * B_ * 320;

    for (int c = 0; c < nc; c++) {
        const int t0 = c * C;
        gemm_in<192, true,  false><<<dim3(3, 4, C), 256, 0, stream>>>(x, gfWi, gfbi, nullptr, xg_c, t0);
        gemm_in<320, false, false><<<dim3(5, 4, C), 256, 0, stream>>>(x, hbfW, hbfb, hbfc, xpf_c, t0);
        gemm_in<320, false, true ><<<dim3(5, 4, C), 256, 0, stream>>>(x, hbbW, hbbb, hbbc, xpb_c, t0);
        recur<<<dim3(192), 256, 0, stream>>>(xg_c, xpf_c, xpb_c, gfWh, gfbh, hbfU, hbbU,
                                             sf, sb, st, t0, C);
    }

    // fast_last (incl. 1-step backward GRU); st holds final forward-GRU h.
    tail1<<<dim3(B_), 64, 0, stream>>>(x, gbWi, gbbi, gbbh, st, fastW, fastb, fastl);

    // attention pooling over stable sequence
    attn_logits<<<dim3(512), 256, 0, stream>>>(sf, sb, attnpW, attnpb, attnsW, attnsb, logit);
    softmax_k<<<dim3(B_), 256, 0, stream>>>(logit);
    ctx_k<<<dim3(B_), 128, 0, stream>>>(logit, sf, sb, stabW, stabb, ctxo);

    // gate + head
    tail2<<<dim3(B_), 128, 0, stream>>>(fastl, ctxo, gW1, gb1, gW2, gb2,
                                        hW1, hb1, hW2, hb2, (float*)d_out);
}

// Round 4
// 1597.597 us; speedup vs baseline: 1.0754x; 1.0754x over previous
//
#include <hip/hip_runtime.h>
#include <math.h>

#define B_ 256
#define T_ 512
#define D_ 128
#define H_ 64

// ---------------- persistent workspace layout (floats) ----------------
static const size_t F_SF    = 0;
static const size_t F_SB    = F_SF + (size_t)T_ * B_ * 64;
static const size_t F_ST    = F_SB + (size_t)T_ * B_ * 64;
static const size_t F_FASTL = F_ST + (size_t)7 * B_ * 64;
static const size_t F_LOG   = F_FASTL + (size_t)B_ * 128;
static const size_t F_CTX   = F_LOG + (size_t)B_ * T_;
static const size_t F_CHUNK = F_CTX + (size_t)B_ * 128;

__device__ __forceinline__ float sigmoidf_(float x) {
    return 1.0f / (1.0f + __expf(-x));
}
__device__ __forceinline__ float tanhf_(float x) {
    float ax = fabsf(x);
    float e  = __expf(-2.0f * ax);
    float t  = (1.0f - e) / (1.0f + e);
    return copysignf(t, x);
}
__device__ __forceinline__ float rl_(float v, int lane) {
    return __int_as_float(__builtin_amdgcn_readlane(__float_as_int(v), lane));
}
__device__ __forceinline__ float wave_sum(float v) {
#pragma unroll
    for (int off = 32; off > 0; off >>= 1) v += __shfl_xor(v, off);
    return v;
}
__device__ __forceinline__ float wave_max(float v) {
#pragma unroll
    for (int off = 32; off > 0; off >>= 1) v = fmaxf(v, __shfl_xor(v, off));
    return v;
}

// ---------------------------------------------------------------------------
// Input GEMM over a chunk of C timesteps (grid.z = C, chunk-local).
// ---------------------------------------------------------------------------
template<int N, bool WGD, bool REV>
__global__ __launch_bounds__(256) void gemm_in(
    const float* __restrict__ x, const float* __restrict__ W,
    const float* __restrict__ b1, const float* __restrict__ b2,
    float* __restrict__ out, int t0)
{
    __shared__ float a_lds[64 * 68];   // [k_local][m] padded
    __shared__ float w_lds[64 * 68];   // [k_local][n] padded

    const int tid = threadIdx.x;
    const int tl  = blockIdx.z;
    const int tg  = t0 + tl;
    const int txi = REV ? (T_ - 1 - tg) : tg;
    const int b0  = blockIdx.y * 64;
    const int g0  = blockIdx.x * 64;

    const int ty = tid >> 4, tx = tid & 15;
    float acc[4][4] = {};

    for (int kh = 0; kh < 2; kh++) {
#pragma unroll
        for (int i = 0; i < 4; i++) {
            int flat = i * 256 + tid;
            int r  = flat >> 4;
            int c4 = flat & 15;
            const float4 v = *reinterpret_cast<const float4*>(
                x + ((size_t)(b0 + r) * T_ + txi) * D_ + kh * 64 + c4 * 4);
            a_lds[(c4 * 4 + 0) * 68 + r] = v.x;
            a_lds[(c4 * 4 + 1) * 68 + r] = v.y;
            a_lds[(c4 * 4 + 2) * 68 + r] = v.z;
            a_lds[(c4 * 4 + 3) * 68 + r] = v.w;
        }
        if (WGD) {
#pragma unroll
            for (int i = 0; i < 4; i++) {
                int flat = i * 256 + tid;
                int r  = flat >> 4;
                int c4 = flat & 15;
                const float4 v = *reinterpret_cast<const float4*>(
                    W + (size_t)(g0 + r) * D_ + kh * 64 + c4 * 4);
                w_lds[(c4 * 4 + 0) * 68 + r] = v.x;
                w_lds[(c4 * 4 + 1) * 68 + r] = v.y;
                w_lds[(c4 * 4 + 2) * 68 + r] = v.z;
                w_lds[(c4 * 4 + 3) * 68 + r] = v.w;
            }
        } else {
#pragma unroll
            for (int i = 0; i < 4; i++) {
                int flat = i * 256 + tid;
                int k  = flat >> 4;
                int c4 = flat & 15;
                const float4 v = *reinterpret_cast<const float4*>(
                    W + (size_t)(kh * 64 + k) * N + g0 + c4 * 4);
                *reinterpret_cast<float4*>(&w_lds[k * 68 + c4 * 4]) = v;
            }
        }
        __syncthreads();
#pragma unroll 8
        for (int k = 0; k < 64; k++) {
            const float4 av = *reinterpret_cast<const float4*>(&a_lds[k * 68 + ty * 4]);
            const float4 wv = *reinterpret_cast<const float4*>(&w_lds[k * 68 + tx * 4]);
            const float am[4] = {av.x, av.y, av.z, av.w};
            const float wn[4] = {wv.x, wv.y, wv.z, wv.w};
#pragma unroll
            for (int mi = 0; mi < 4; mi++)
#pragma unroll
                for (int ni = 0; ni < 4; ni++)
                    acc[mi][ni] = fmaf(am[mi], wn[ni], acc[mi][ni]);
        }
        __syncthreads();
    }

    float bias[4];
#pragma unroll
    for (int ni = 0; ni < 4; ni++) {
        float bb = b1[g0 + tx * 4 + ni];
        if (b2 != nullptr) bb += b2[g0 + tx * 4 + ni];
        bias[ni] = bb;
    }
#pragma unroll
    for (int mi = 0; mi < 4; mi++) {
        float4 o;
        o.x = acc[mi][0] + bias[0];
        o.y = acc[mi][1] + bias[1];
        o.z = acc[mi][2] + bias[2];
        o.w = acc[mi][3] + bias[3];
        *reinterpret_cast<float4*>(
            out + ((size_t)tl * B_ + b0 + ty * 4 + mi) * N + g0 + tx * 4) = o;
    }
}

// ---------------------------------------------------------------------------
// Recurrences for one time-chunk [t0, t0+C). One wave per chain, no LDS,
// no barriers. chain = blockIdx.x*4 + waveid:
//   [0,256)   GRU forward  (state h)
//   [256,512) HB forward   (state h,k,kp; writes sf)
//   [512,768) HB backward  (writes sb at reversed t)
// Weights are pinned into VGPRs via empty asm (defeats load remat/sink —
// round-3 counters showed VGPR=176: compiler was re-fetching weights every
// step, recur was 8880 cyc/step vs ~950 issue floor).
// h broadcast via v_readlane (SGPR operand to FMA), not LDS.
// ---------------------------------------------------------------------------
__global__ __launch_bounds__(256, 1) void recur(
    const float* __restrict__ xg_c, const float* __restrict__ xpf_c,
    const float* __restrict__ xpb_c,
    const float* __restrict__ gWh, const float* __restrict__ gbh,
    const float* __restrict__ Uf,  const float* __restrict__ Ub,
    float* __restrict__ sf, float* __restrict__ sb,
    float* __restrict__ state, int t0, int C)
{
    const int tid   = threadIdx.x;
    const int w     = tid & 63;
    const int wb    = tid >> 6;
    const int chain = blockIdx.x * 4 + wb;   // 0..767

    if (chain < 256) {
        // ---------------- GRU forward ----------------
        const int batch = chain;
        float* stH = state;
        float h = (t0 == 0) ? 0.0f : stH[(size_t)batch * 64 + w];

        float wh0[64], wh1[64], wh2[64];
#pragma unroll
        for (int j = 0; j < 64; j++) {
            wh0[j] = gWh[(size_t)(0 * 64 + w) * 64 + j];
            wh1[j] = gWh[(size_t)(1 * 64 + w) * 64 + j];
            wh2[j] = gWh[(size_t)(2 * 64 + w) * 64 + j];
            asm volatile("" : "+v"(wh0[j]), "+v"(wh1[j]), "+v"(wh2[j]));
        }
        const float bh0 = gbh[w], bh1 = gbh[64 + w], bh2 = gbh[128 + w];

        float xv0, xv1, xv2;
        {
            const float* p = xg_c + (size_t)batch * 192;
            xv0 = p[w]; xv1 = p[64 + w]; xv2 = p[128 + w];
        }
        for (int t = 0; t < C; t++) {
            float xn0, xn1, xn2;
            {
                int tn = (t + 1 < C) ? (t + 1) : t;
                const float* pn = xg_c + ((size_t)tn * B_ + batch) * 192;
                xn0 = pn[w]; xn1 = pn[64 + w]; xn2 = pn[128 + w];
            }
            float a0 = bh0, a1 = bh1, a2 = bh2;
#pragma unroll
            for (int j = 0; j < 64; j++) {
                const float hj = rl_(h, j);
                a0 = fmaf(hj, wh0[j], a0);
                a1 = fmaf(hj, wh1[j], a1);
                a2 = fmaf(hj, wh2[j], a2);
            }
            float r = sigmoidf_(xv0 + a0);
            float z = sigmoidf_(xv1 + a1);
            float n = tanhf_(xv2 + r * a2);
            h = (1.0f - z) * n + z * h;
            xv0 = xn0; xv1 = xn1; xv2 = xn2;
        }
        stH[(size_t)batch * 64 + w] = h;
    } else {
        // ---------------- Hierarchical block (f / b) ----------------
        const int dir   = (chain >= 512);
        const int batch = chain - (dir ? 512 : 256);
        const float* U  = dir ? Ub : Uf;
        const float* xp = dir ? xpb_c : xpf_c;
        float* outbuf   = dir ? sb : sf;
        float* stH  = state + (size_t)(1 + dir * 3) * B_ * 64;
        float* stK  = stH + (size_t)B_ * 64;
        float* stKp = stK + (size_t)B_ * 64;

        float h, k, kp;
        if (t0 == 0) { h = 0.0f; k = 0.0f; kp = 0.0f; }
        else {
            h  = stH [(size_t)batch * 64 + w];
            k  = stK [(size_t)batch * 64 + w];
            kp = stKp[(size_t)batch * 64 + w];
        }

        float u0[64], u1[64], u2[64], u3[64], u4[64];
#pragma unroll
        for (int j = 0; j < 64; j++) {
            const float* Uj = U + (size_t)j * 320 + w;
            u0[j] = Uj[0];
            u1[j] = Uj[64];
            u2[j] = Uj[128];
            u3[j] = Uj[192];
            u4[j] = Uj[256];
            asm volatile("" : "+v"(u0[j]), "+v"(u1[j]), "+v"(u2[j]),
                              "+v"(u3[j]), "+v"(u4[j]));
        }

        float xv0, xv1, xv2, xv3, xv4;
        {
            const float* p = xp + (size_t)batch * 320;
            xv0 = p[w]; xv1 = p[64 + w]; xv2 = p[128 + w];
            xv3 = p[192 + w]; xv4 = p[256 + w];
        }
        for (int t = 0; t < C; t++) {
            float xn0, xn1, xn2, xn3, xn4;
            {
                int tn = (t + 1 < C) ? (t + 1) : t;
                const float* pn = xp + ((size_t)tn * B_ + batch) * 320;
                xn0 = pn[w]; xn1 = pn[64 + w]; xn2 = pn[128 + w];
                xn3 = pn[192 + w]; xn4 = pn[256 + w];
            }
            float a0 = 0.f, a1 = 0.f, a2 = 0.f, a3 = 0.f, a4 = 0.f;
#pragma unroll
            for (int j = 0; j < 64; j++) {
                const float hj = rl_(h, j);
                a0 = fmaf(hj, u0[j], a0);
                a1 = fmaf(hj, u1[j], a1);
                a2 = fmaf(hj, u2[j], a2);
                a3 = fmaf(hj, u3[j], a3);
                a4 = fmaf(hj, u4[j], a4);
            }
            float f   = sigmoidf_(xv0 + a0);
            float ii  = sigmoidf_(xv1 + a1);
            float o   = sigmoidf_(xv2 + a2);
            float uu  = sigmoidf_(xv3 + a3);
            float tkc = tanhf_(xv4 + a4);
            kp = uu * tkc + (1.0f - uu) * kp;
            k  = f * k + ii * kp;
            h  = o * tanhf_(k);
            int tg   = t0 + t;
            int tout = dir ? (T_ - 1 - tg) : tg;
            outbuf[((size_t)tout * B_ + batch) * 64 + w] = h;
            xv0 = xn0; xv1 = xn1; xv2 = xn2; xv3 = xn3; xv4 = xn4;
        }
        stH [(size_t)batch * 64 + w] = h;
        stK [(size_t)batch * 64 + w] = k;
        stKp[(size_t)batch * 64 + w] = kp;
    }
}

// ---------------------------------------------------------------------------
// tail1: backward-GRU single step (h0=0 => hg = bh) + fast_last projection.
// ---------------------------------------------------------------------------
__global__ __launch_bounds__(64) void tail1(
    const float* __restrict__ x, const float* __restrict__ Wib,
    const float* __restrict__ bib, const float* __restrict__ bhb,
    const float* __restrict__ hfl, const float* __restrict__ fW,
    const float* __restrict__ fb, float* __restrict__ fastl)
{
    __shared__ float xrow[128];
    __shared__ float inb[128];
    const int b = blockIdx.x;
    const int l = threadIdx.x;
    xrow[l]      = x[((size_t)b * T_ + (T_ - 1)) * D_ + l];
    xrow[64 + l] = x[((size_t)b * T_ + (T_ - 1)) * D_ + 64 + l];
    inb[l] = hfl[(size_t)b * 64 + l];
    __syncthreads();
    float a0 = bib[l], a1 = bib[64 + l], a2 = bib[128 + l];
#pragma unroll 8
    for (int d = 0; d < 128; d++) {
        float xd = xrow[d];
        a0 = fmaf(xd, Wib[(size_t)l * 128 + d], a0);
        a1 = fmaf(xd, Wib[(size_t)(64 + l) * 128 + d], a1);
        a2 = fmaf(xd, Wib[(size_t)(128 + l) * 128 + d], a2);
    }
    float r = sigmoidf_(a0 + bhb[l]);
    float z = sigmoidf_(a1 + bhb[64 + l]);
    float n = tanhf_(a2 + r * bhb[128 + l]);
    inb[64 + l] = (1.0f - z) * n;
    __syncthreads();
    float acc0 = fb[l], acc1 = fb[64 + l];
#pragma unroll 8
    for (int i2 = 0; i2 < 128; i2++) {
        float v = inb[i2];
        acc0 = fmaf(v, fW[(size_t)i2 * 128 + l], acc0);
        acc1 = fmaf(v, fW[(size_t)i2 * 128 + 64 + l], acc1);
    }
    fastl[(size_t)b * 128 + l]      = acc0;
    fastl[(size_t)b * 128 + 64 + l] = acc1;
}

// ---------------------------------------------------------------------------
// Fused attention logits: logits[b,t] = tanh(stable@Wp + bp) @ Ws + bs
// ---------------------------------------------------------------------------
__global__ __launch_bounds__(256) void attn_logits(
    const float* __restrict__ sf, const float* __restrict__ sb,
    const float* __restrict__ Wp, const float* __restrict__ bp,
    const float* __restrict__ Ws, const float* __restrict__ bs,
    float* __restrict__ logits)
{
    __shared__ float wp_t[64 * 129];
    __shared__ float s_lds[4][132];
    __shared__ float bp_l[64], ws_l[64];
    const int tid = threadIdx.x;
#pragma unroll
    for (int i = 0; i < 32; i++) {
        int idx = i * 256 + tid;
        int d = idx >> 6, g = idx & 63;
        wp_t[g * 129 + d] = Wp[idx];
    }
    if (tid < 64) { bp_l[tid] = bp[tid]; ws_l[tid] = Ws[tid]; }
    __syncthreads();
    const int wave = tid >> 6, l = tid & 63;
    for (int it = 0; it < 64; it++) {
        int p  = blockIdx.x * 256 + wave * 64 + it;
        int bb = p >> 9;
        int t  = p & 511;
        s_lds[wave][l]      = sf[((size_t)t * B_ + bb) * 64 + l];
        s_lds[wave][64 + l] = sb[((size_t)t * B_ + bb) * 64 + l];
        float acc = bp_l[l];
#pragma unroll 8
        for (int d = 0; d < 128; d++)
            acc = fmaf(s_lds[wave][d], wp_t[l * 129 + d], acc);
        float v = tanhf_(acc) * ws_l[l];
        v = wave_sum(v);
        if (l == 0) logits[(size_t)bb * T_ + t] = v + bs[0];
    }
}

__global__ __launch_bounds__(256) void softmax_k(float* __restrict__ logits)
{
    __shared__ float red[8];
    const int b = blockIdx.x, tid = threadIdx.x;
    const int wave = tid >> 6, l = tid & 63;
    float* row = logits + (size_t)b * T_;
    float l0 = row[tid], l1 = row[tid + 256];
    float m = wave_max(fmaxf(l0, l1));
    if (l == 0) red[wave] = m;
    __syncthreads();
    m = fmaxf(fmaxf(red[0], red[1]), fmaxf(red[2], red[3]));
    float e0 = __expf(l0 - m), e1 = __expf(l1 - m);
    float s = wave_sum(e0 + e1);
    if (l == 0) red[4 + wave] = s;
    __syncthreads();
    s = red[4] + red[5] + red[6] + red[7];
    row[tid]       = e0 / s;
    row[tid + 256] = e1 / s;
}

__global__ __launch_bounds__(128) void ctx_k(
    const float* __restrict__ wsm, const float* __restrict__ sf,
    const float* __restrict__ sb, const float* __restrict__ stW,
    const float* __restrict__ stb, float* __restrict__ ctxo)
{
    __shared__ float wrow[512];
    __shared__ float cpre[128];
    const int b = blockIdx.x, tid = threadIdx.x;
#pragma unroll
    for (int i = 0; i < 4; i++) wrow[i * 128 + tid] = wsm[(size_t)b * T_ + i * 128 + tid];
    __syncthreads();
    const float* src = (tid < 64) ? sf : sb;
    const int d = tid & 63;
    float acc = 0.0f;
#pragma unroll 4
    for (int t = 0; t < 512; t++)
        acc = fmaf(wrow[t], src[((size_t)t * B_ + b) * 64 + d], acc);
    cpre[tid] = acc;
    __syncthreads();
    float a2 = stb[tid];
#pragma unroll 8
    for (int i2 = 0; i2 < 128; i2++)
        a2 = fmaf(cpre[i2], stW[(size_t)i2 * 128 + tid], a2);
    ctxo[(size_t)b * 128 + tid] = a2;
}

__global__ __launch_bounds__(128) void tail2(
    const float* __restrict__ fastl, const float* __restrict__ ctxo,
    const float* __restrict__ gW1, const float* __restrict__ gb1,
    const float* __restrict__ gW2, const float* __restrict__ gb2,
    const float* __restrict__ hW1, const float* __restrict__ hb1,
    const float* __restrict__ hW2, const float* __restrict__ hb2,
    float* __restrict__ outp)
{
    __shared__ float gin[256];
    __shared__ float outv[384];
    __shared__ float red2[2];
    const int b = blockIdx.x, tid = threadIdx.x;
    gin[tid]       = fastl[(size_t)b * 128 + tid];
    gin[128 + tid] = ctxo[(size_t)b * 128 + tid];
    __syncthreads();
    float a = gb1[tid];
#pragma unroll 8
    for (int i = 0; i < 256; i++)
        a = fmaf(gin[i], gW1[(size_t)i * 128 + tid], a);
    float gh = fmaxf(a, 0.0f);
    float v = wave_sum(gh * gW2[tid]);
    if ((tid & 63) == 0) red2[tid >> 6] = v;
    __syncthreads();
    float gate = sigmoidf_(red2[0] + red2[1] + gb2[0]);
    float fl = gin[tid], sc = gin[128 + tid];
    outv[tid]       = gate * fl + (1.0f - gate) * sc;
    outv[128 + tid] = fl;
    outv[256 + tid] = sc;
    __syncthreads();
    float a1 = hb1[tid];
#pragma unroll 8
    for (int i = 0; i < 384; i++)
        a1 = fmaf(outv[i], hW1[(size_t)i * 128 + tid], a1);
    float h1v = fmaxf(a1, 0.0f);
    float vv = wave_sum(h1v * hW2[tid]);
    if ((tid & 63) == 0) red2[tid >> 6] = vv;
    __syncthreads();
    if (tid == 0) outp[b] = red2[0] + red2[1] + hb2[0];
}

extern "C" void kernel_launch(void* const* d_in, const int* in_sizes, int n_in,
                              void* d_out, int out_size, void* d_ws, size_t ws_size,
                              hipStream_t stream)
{
    (void)in_sizes; (void)n_in; (void)out_size;
    const float* x      = (const float*)d_in[0];
    const float* gfWi   = (const float*)d_in[1];
    const float* gfWh   = (const float*)d_in[2];
    const float* gfbi   = (const float*)d_in[3];
    const float* gfbh   = (const float*)d_in[4];
    const float* gbWi   = (const float*)d_in[5];
    const float* gbbi   = (const float*)d_in[7];
    const float* gbbh   = (const float*)d_in[8];
    const float* hbfW   = (const float*)d_in[9];
    const float* hbfb   = (const float*)d_in[10];
    const float* hbfU   = (const float*)d_in[11];
    const float* hbfc   = (const float*)d_in[12];
    const float* hbbW   = (const float*)d_in[13];
    const float* hbbb   = (const float*)d_in[14];
    const float* hbbU   = (const float*)d_in[15];
    const float* hbbc   = (const float*)d_in[16];
    const float* fastW  = (const float*)d_in[17];
    const float* fastb  = (const float*)d_in[18];
    const float* stabW  = (const float*)d_in[19];
    const float* stabb  = (const float*)d_in[20];
    const float* attnpW = (const float*)d_in[21];
    const float* attnpb = (const float*)d_in[22];
    const float* attnsW = (const float*)d_in[23];
    const float* attnsb = (const float*)d_in[24];
    const float* gW1    = (const float*)d_in[25];
    const float* gb1    = (const float*)d_in[26];
    const float* gW2    = (const float*)d_in[27];
    const float* gb2    = (const float*)d_in[28];
    const float* hW1    = (const float*)d_in[29];
    const float* hb1    = (const float*)d_in[30];
    const float* hW2    = (const float*)d_in[31];
    const float* hb2    = (const float*)d_in[32];

    float* ws    = (float*)d_ws;
    float* sf    = ws + F_SF;
    float* sb    = ws + F_SB;
    float* st    = ws + F_ST;
    float* fastl = ws + F_FASTL;
    float* logit = ws + F_LOG;
    float* ctxo  = ws + F_CTX;

    // Adaptive chunk size from ws_size (deterministic per run -> graph-safe).
    const size_t wsf = ws_size / sizeof(float);
    int C = T_;
    while (C > 1 && F_CHUNK + (size_t)C * B_ * 832 > wsf) C >>= 1;
    const int nc = T_ / C;

    float* xg_c  = ws + F_CHUNK;
    float* xpf_c = xg_c  + (size_t)C * B_ * 192;
    float* xpb_c = xpf_c + (size_t)C * B_ * 320;

    for (int c = 0; c < nc; c++) {
        const int t0 = c * C;
        gemm_in<192, true,  false><<<dim3(3, 4, C), 256, 0, stream>>>(x, gfWi, gfbi, nullptr, xg_c, t0);
        gemm_in<320, false, false><<<dim3(5, 4, C), 256, 0, stream>>>(x, hbfW, hbfb, hbfc, xpf_c, t0);
        gemm_in<320, false, true ><<<dim3(5, 4, C), 256, 0, stream>>>(x, hbbW, hbbb, hbbc, xpb_c, t0);
        recur<<<dim3(192), 256, 0, stream>>>(xg_c, xpf_c, xpb_c, gfWh, gfbh, hbfU, hbbU,
                                             sf, sb, st, t0, C);
    }

    tail1<<<dim3(B_), 64, 0, stream>>>(x, gbWi, gbbi, gbbh, st, fastW, fastb, fastl);

    attn_logits<<<dim3(512), 256, 0, stream>>>(sf, sb, attnpW, attnpb, attnsW, attnsb, logit);
    softmax_k<<<dim3(B_), 256, 0, stream>>>(logit);
    ctx_k<<<dim3(B_), 128, 0, stream>>>(logit, sf, sb, stabW, stabb, ctxo);

    tail2<<<dim3(B_), 128, 0, stream>>>(fastl, ctxo, gW1, gb1, gW2, gb2,
                                        hW1, hb1, hW2, hb2, (float*)d_out);
}

// Round 5
// 1312.877 us; speedup vs baseline: 1.3086x; 1.2169x over previous
//
#include <hip/hip_runtime.h>
#include <math.h>

#define B_ 256
#define T_ 512
#define D_ 128
#define H_ 64

// ---------------- persistent workspace layout (floats) ----------------
static const size_t F_SF    = 0;
static const size_t F_SB    = F_SF + (size_t)T_ * B_ * 64;
static const size_t F_ST    = F_SB + (size_t)T_ * B_ * 64;
static const size_t F_FASTL = F_ST + (size_t)7 * B_ * 64;
static const size_t F_LOG   = F_FASTL + (size_t)B_ * 128;
static const size_t F_CTX   = F_LOG + (size_t)B_ * T_;
static const size_t F_CHUNK = F_CTX + (size_t)B_ * 128;

__device__ __forceinline__ float sigmoidf_(float x) {
    return 1.0f / (1.0f + __expf(-x));
}
__device__ __forceinline__ float tanhf_(float x) {
    float ax = fabsf(x);
    float e  = __expf(-2.0f * ax);
    float t  = (1.0f - e) / (1.0f + e);
    return copysignf(t, x);
}
__device__ __forceinline__ float rl_(float v, int lane) {
    return __int_as_float(__builtin_amdgcn_readlane(__float_as_int(v), lane));
}
__device__ __forceinline__ float wave_sum(float v) {
#pragma unroll
    for (int off = 32; off > 0; off >>= 1) v += __shfl_xor(v, off);
    return v;
}
__device__ __forceinline__ float wave_max(float v) {
#pragma unroll
    for (int off = 32; off > 0; off >>= 1) v = fmaxf(v, __shfl_xor(v, off));
    return v;
}

// j-range partial accumulate helpers (literal readlane indices)
template<int BASE>
__device__ __forceinline__ void hb_acc(float h,
    const float* u0, const float* u1, const float* u2,
    const float* u3, const float* u4,
    float& a0, float& a1, float& a2, float& a3, float& a4)
{
#pragma unroll
    for (int jj = 0; jj < 32; jj++) {
        const float hj = rl_(h, BASE + jj);
        a0 = fmaf(hj, u0[jj], a0);
        a1 = fmaf(hj, u1[jj], a1);
        a2 = fmaf(hj, u2[jj], a2);
        a3 = fmaf(hj, u3[jj], a3);
        a4 = fmaf(hj, u4[jj], a4);
    }
}
template<int BASE>
__device__ __forceinline__ void gru_acc(float h,
    const float* w0, const float* w1, const float* w2,
    float& a0, float& a1, float& a2)
{
#pragma unroll
    for (int jj = 0; jj < 32; jj++) {
        const float hj = rl_(h, BASE + jj);
        a0 = fmaf(hj, w0[jj], a0);
        a1 = fmaf(hj, w1[jj], a1);
        a2 = fmaf(hj, w2[jj], a2);
    }
}

// ---------------------------------------------------------------------------
// Input GEMM over a chunk of C timesteps. Tile 128(M=batch) x 64(N=gates),
// K=128 in 2 halves. 8x4 acc/thread. XOR swizzle (idx ^ ((k>>2)&7)<<2) on the
// staging scatter + compute reads turns the 8-way bank conflict into 2-way.
// ---------------------------------------------------------------------------
template<int N, bool WGD, bool REV>
__global__ __launch_bounds__(256, 1) void gemm_in(
    const float* __restrict__ x, const float* __restrict__ W,
    const float* __restrict__ b1, const float* __restrict__ b2,
    float* __restrict__ out, int t0)
{
    __shared__ float a_lds[64 * 132];   // [k][m^swz] padded
    __shared__ float w_lds[64 * 68];    // [k][n^swz] padded

    const int tid = threadIdx.x;
    const int tl  = blockIdx.z;
    const int tg  = t0 + tl;
    const int txi = REV ? (T_ - 1 - tg) : tg;
    const int b0  = blockIdx.y * 128;
    const int g0  = blockIdx.x * 64;

    const int ty = tid >> 4, tx = tid & 15;
    float acc[8][4] = {};

    for (int kh = 0; kh < 2; kh++) {
        // stage A: 128 m x 64 k (swizzled scatter, 2-way conflicts only)
#pragma unroll
        for (int i = 0; i < 8; i++) {
            int flat = i * 256 + tid;      // 0..2047
            int r    = flat >> 4;          // m 0..127
            int c4   = flat & 15;          // k-quad
            const float4 v = *reinterpret_cast<const float4*>(
                x + ((size_t)(b0 + r) * T_ + txi) * D_ + kh * 64 + c4 * 4);
            const int rs = r ^ ((c4 & 7) << 2);
            a_lds[(c4 * 4 + 0) * 132 + rs] = v.x;
            a_lds[(c4 * 4 + 1) * 132 + rs] = v.y;
            a_lds[(c4 * 4 + 2) * 132 + rs] = v.z;
            a_lds[(c4 * 4 + 3) * 132 + rs] = v.w;
        }
        // stage W: 64 k x 64 n
        if (WGD) {
#pragma unroll
            for (int i = 0; i < 4; i++) {
                int flat = i * 256 + tid;   // 0..1023
                int r    = flat >> 4;       // n 0..63
                int c4   = flat & 15;       // k-quad
                const float4 v = *reinterpret_cast<const float4*>(
                    W + (size_t)(g0 + r) * D_ + kh * 64 + c4 * 4);
                const int rs = r ^ ((c4 & 7) << 2);
                w_lds[(c4 * 4 + 0) * 68 + rs] = v.x;
                w_lds[(c4 * 4 + 1) * 68 + rs] = v.y;
                w_lds[(c4 * 4 + 2) * 68 + rs] = v.z;
                w_lds[(c4 * 4 + 3) * 68 + rs] = v.w;
            }
        } else {
#pragma unroll
            for (int i = 0; i < 4; i++) {
                int flat = i * 256 + tid;
                int k    = flat >> 4;       // k 0..63
                int c4   = flat & 15;       // n-quad
                const float4 v = *reinterpret_cast<const float4*>(
                    W + (size_t)(kh * 64 + k) * N + g0 + c4 * 4);
                const int ns = (c4 * 4) ^ (((k >> 2) & 7) << 2);
                *reinterpret_cast<float4*>(&w_lds[k * 68 + ns]) = v;
            }
        }
        __syncthreads();
#pragma unroll 8
        for (int k = 0; k < 64; k++) {
            const int sw = ((k >> 2) & 7) << 2;
            const float4 am0 = *reinterpret_cast<const float4*>(
                &a_lds[k * 132 + ((ty * 8) ^ sw)]);
            const float4 am1 = *reinterpret_cast<const float4*>(
                &a_lds[k * 132 + ((ty * 8 + 4) ^ sw)]);
            const float4 wn4 = *reinterpret_cast<const float4*>(
                &w_lds[k * 68 + ((tx * 4) ^ sw)]);
            const float am[8] = {am0.x, am0.y, am0.z, am0.w,
                                 am1.x, am1.y, am1.z, am1.w};
            const float wn[4] = {wn4.x, wn4.y, wn4.z, wn4.w};
#pragma unroll
            for (int mi = 0; mi < 8; mi++)
#pragma unroll
                for (int ni = 0; ni < 4; ni++)
                    acc[mi][ni] = fmaf(am[mi], wn[ni], acc[mi][ni]);
        }
        __syncthreads();
    }

    float bias[4];
#pragma unroll
    for (int ni = 0; ni < 4; ni++) {
        float bb = b1[g0 + tx * 4 + ni];
        if (b2 != nullptr) bb += b2[g0 + tx * 4 + ni];
        bias[ni] = bb;
    }
#pragma unroll
    for (int mi = 0; mi < 8; mi++) {
        float4 o;
        o.x = acc[mi][0] + bias[0];
        o.y = acc[mi][1] + bias[1];
        o.z = acc[mi][2] + bias[2];
        o.w = acc[mi][3] + bias[3];
        *reinterpret_cast<float4*>(
            out + ((size_t)tl * B_ + b0 + ty * 8 + mi) * N + g0 + tx * 4) = o;
    }
}

// ---------------------------------------------------------------------------
// Recurrences, j-split across 2 waves per chain (gfx950 VALU addresses only
// v0-v255, so 320 weights/lane cannot be register-resident; 160 can).
// Block = 384 threads: waves 0..3 = 2 HB chains (pair p=0/1), waves 4,5 =
// 1 GRU chain. 256 blocks -> 1/CU. Partial gate sums exchanged via LDS,
// one barrier per step (double-buffered by t&1). Both waves of a pair
// redundantly compute identical state (h,k,kp) -> no second barrier.
// ---------------------------------------------------------------------------
__global__ __launch_bounds__(384, 1) void recur(
    const float* __restrict__ xg_c, const float* __restrict__ xpf_c,
    const float* __restrict__ xpb_c,
    const float* __restrict__ gWh, const float* __restrict__ gbh,
    const float* __restrict__ Uf,  const float* __restrict__ Ub,
    float* __restrict__ sf, float* __restrict__ sb,
    float* __restrict__ state, int t0, int C)
{
    __shared__ float hpart[2][2][2][5][64];  // [buf][chain][p][gate][w]
    __shared__ float gpart[2][2][3][64];     // [buf][p][gate][w]
    const int tid = threadIdx.x;
    const int w   = tid & 63;
    const int wv  = tid >> 6;   // 0..5

    if (wv < 4) {
        // ---------------- HB chains (2 per block) ----------------
        const int lc    = wv >> 1;
        const int p     = wv & 1;
        const int hb    = blockIdx.x * 2 + lc;     // 0..511
        const int dir   = hb >= 256 ? 1 : 0;
        const int batch = hb - (dir ? 256 : 0);
        const float* U  = dir ? Ub : Uf;
        const float* xp = dir ? xpb_c : xpf_c;
        float* outbuf   = dir ? sb : sf;
        float* stH  = state + (size_t)(1 + dir * 3) * B_ * 64;
        float* stK  = stH + (size_t)B_ * 64;
        float* stKp = stK + (size_t)B_ * 64;

        float h, k, kp;
        if (t0 == 0) { h = 0.0f; k = 0.0f; kp = 0.0f; }
        else {
            h  = stH [(size_t)batch * 64 + w];
            k  = stK [(size_t)batch * 64 + w];
            kp = stKp[(size_t)batch * 64 + w];
        }

        // weights for j in [32p, 32p+32): 160 floats/lane
        float u0[32], u1[32], u2[32], u3[32], u4[32];
#pragma unroll
        for (int jj = 0; jj < 32; jj++) {
            const float* Uj = U + (size_t)(p * 32 + jj) * 320 + w;
            u0[jj] = Uj[0];
            u1[jj] = Uj[64];
            u2[jj] = Uj[128];
            u3[jj] = Uj[192];
            u4[jj] = Uj[256];
            asm volatile("" : "+v"(u0[jj]), "+v"(u1[jj]), "+v"(u2[jj]),
                              "+v"(u3[jj]), "+v"(u4[jj]));
        }

        float xv0, xv1, xv2, xv3, xv4;
        {
            const float* pp = xp + (size_t)batch * 320;
            xv0 = pp[w]; xv1 = pp[64 + w]; xv2 = pp[128 + w];
            xv3 = pp[192 + w]; xv4 = pp[256 + w];
        }
        for (int t = 0; t < C; t++) {
            float xn0, xn1, xn2, xn3, xn4;
            {
                int tn = (t + 1 < C) ? (t + 1) : t;
                const float* pn = xp + ((size_t)tn * B_ + batch) * 320;
                xn0 = pn[w]; xn1 = pn[64 + w]; xn2 = pn[128 + w];
                xn3 = pn[192 + w]; xn4 = pn[256 + w];
            }
            float a0 = 0.f, a1 = 0.f, a2 = 0.f, a3 = 0.f, a4 = 0.f;
            if (p == 0) hb_acc<0 >(h, u0, u1, u2, u3, u4, a0, a1, a2, a3, a4);
            else        hb_acc<32>(h, u0, u1, u2, u3, u4, a0, a1, a2, a3, a4);

            const int bf = t & 1;
            hpart[bf][lc][p][0][w] = a0;
            hpart[bf][lc][p][1][w] = a1;
            hpart[bf][lc][p][2][w] = a2;
            hpart[bf][lc][p][3][w] = a3;
            hpart[bf][lc][p][4][w] = a4;
            __syncthreads();
            a0 += hpart[bf][lc][1 - p][0][w];
            a1 += hpart[bf][lc][1 - p][1][w];
            a2 += hpart[bf][lc][1 - p][2][w];
            a3 += hpart[bf][lc][1 - p][3][w];
            a4 += hpart[bf][lc][1 - p][4][w];

            float f   = sigmoidf_(xv0 + a0);
            float ii  = sigmoidf_(xv1 + a1);
            float o   = sigmoidf_(xv2 + a2);
            float uu  = sigmoidf_(xv3 + a3);
            float tkc = tanhf_(xv4 + a4);
            kp = uu * tkc + (1.0f - uu) * kp;
            k  = f * k + ii * kp;
            h  = o * tanhf_(k);
            if (p == 0) {
                int tg   = t0 + t;
                int tout = dir ? (T_ - 1 - tg) : tg;
                outbuf[((size_t)tout * B_ + batch) * 64 + w] = h;
            }
            xv0 = xn0; xv1 = xn1; xv2 = xn2; xv3 = xn3; xv4 = xn4;
        }
        if (p == 0) {
            stH [(size_t)batch * 64 + w] = h;
            stK [(size_t)batch * 64 + w] = k;
            stKp[(size_t)batch * 64 + w] = kp;
        }
    } else {
        // ---------------- GRU forward (1 per block) ----------------
        const int p     = wv - 4;
        const int batch = blockIdx.x;
        float* stH = state;
        float h = (t0 == 0) ? 0.0f : stH[(size_t)batch * 64 + w];

        float wh0[32], wh1[32], wh2[32];
#pragma unroll
        for (int jj = 0; jj < 32; jj++) {
            const int j = p * 32 + jj;
            wh0[jj] = gWh[(size_t)(0 * 64 + w) * 64 + j];
            wh1[jj] = gWh[(size_t)(1 * 64 + w) * 64 + j];
            wh2[jj] = gWh[(size_t)(2 * 64 + w) * 64 + j];
            asm volatile("" : "+v"(wh0[jj]), "+v"(wh1[jj]), "+v"(wh2[jj]));
        }
        const float bh0 = gbh[w], bh1 = gbh[64 + w], bh2 = gbh[128 + w];

        float xv0, xv1, xv2;
        {
            const float* pp = xg_c + (size_t)batch * 192;
            xv0 = pp[w]; xv1 = pp[64 + w]; xv2 = pp[128 + w];
        }
        for (int t = 0; t < C; t++) {
            float xn0, xn1, xn2;
            {
                int tn = (t + 1 < C) ? (t + 1) : t;
                const float* pn = xg_c + ((size_t)tn * B_ + batch) * 192;
                xn0 = pn[w]; xn1 = pn[64 + w]; xn2 = pn[128 + w];
            }
            float a0 = 0.f, a1 = 0.f, a2 = 0.f;
            if (p == 0) gru_acc<0 >(h, wh0, wh1, wh2, a0, a1, a2);
            else        gru_acc<32>(h, wh0, wh1, wh2, a0, a1, a2);

            const int bf = t & 1;
            gpart[bf][p][0][w] = a0;
            gpart[bf][p][1][w] = a1;
            gpart[bf][p][2][w] = a2;
            __syncthreads();
            a0 += gpart[bf][1 - p][0][w];
            a1 += gpart[bf][1 - p][1][w];
            a2 += gpart[bf][1 - p][2][w];

            float r = sigmoidf_(xv0 + bh0 + a0);
            float z = sigmoidf_(xv1 + bh1 + a1);
            float n = tanhf_(xv2 + r * (bh2 + a2));
            h = (1.0f - z) * n + z * h;
            xv0 = xn0; xv1 = xn1; xv2 = xn2;
        }
        if (p == 0) stH[(size_t)batch * 64 + w] = h;
    }
}

// ---------------------------------------------------------------------------
// tail1: backward-GRU single step (h0=0 => hg = bh) + fast_last projection.
// ---------------------------------------------------------------------------
__global__ __launch_bounds__(64) void tail1(
    const float* __restrict__ x, const float* __restrict__ Wib,
    const float* __restrict__ bib, const float* __restrict__ bhb,
    const float* __restrict__ hfl, const float* __restrict__ fW,
    const float* __restrict__ fb, float* __restrict__ fastl)
{
    __shared__ float xrow[128];
    __shared__ float inb[128];
    const int b = blockIdx.x;
    const int l = threadIdx.x;
    xrow[l]      = x[((size_t)b * T_ + (T_ - 1)) * D_ + l];
    xrow[64 + l] = x[((size_t)b * T_ + (T_ - 1)) * D_ + 64 + l];
    inb[l] = hfl[(size_t)b * 64 + l];
    __syncthreads();
    float a0 = bib[l], a1 = bib[64 + l], a2 = bib[128 + l];
#pragma unroll 8
    for (int d = 0; d < 128; d++) {
        float xd = xrow[d];
        a0 = fmaf(xd, Wib[(size_t)l * 128 + d], a0);
        a1 = fmaf(xd, Wib[(size_t)(64 + l) * 128 + d], a1);
        a2 = fmaf(xd, Wib[(size_t)(128 + l) * 128 + d], a2);
    }
    float r = sigmoidf_(a0 + bhb[l]);
    float z = sigmoidf_(a1 + bhb[64 + l]);
    float n = tanhf_(a2 + r * bhb[128 + l]);
    inb[64 + l] = (1.0f - z) * n;
    __syncthreads();
    float acc0 = fb[l], acc1 = fb[64 + l];
#pragma unroll 8
    for (int i2 = 0; i2 < 128; i2++) {
        float v = inb[i2];
        acc0 = fmaf(v, fW[(size_t)i2 * 128 + l], acc0);
        acc1 = fmaf(v, fW[(size_t)i2 * 128 + 64 + l], acc1);
    }
    fastl[(size_t)b * 128 + l]      = acc0;
    fastl[(size_t)b * 128 + 64 + l] = acc1;
}

// ---------------------------------------------------------------------------
// Fused attention logits: logits[b,t] = tanh(stable@Wp + bp) @ Ws + bs
// ---------------------------------------------------------------------------
__global__ __launch_bounds__(256) void attn_logits(
    const float* __restrict__ sf, const float* __restrict__ sb,
    const float* __restrict__ Wp, const float* __restrict__ bp,
    const float* __restrict__ Ws, const float* __restrict__ bs,
    float* __restrict__ logits)
{
    __shared__ float wp_t[64 * 129];
    __shared__ float s_lds[4][132];
    __shared__ float bp_l[64], ws_l[64];
    const int tid = threadIdx.x;
#pragma unroll
    for (int i = 0; i < 32; i++) {
        int idx = i * 256 + tid;
        int d = idx >> 6, g = idx & 63;
        wp_t[g * 129 + d] = Wp[idx];
    }
    if (tid < 64) { bp_l[tid] = bp[tid]; ws_l[tid] = Ws[tid]; }
    __syncthreads();
    const int wave = tid >> 6, l = tid & 63;
    for (int it = 0; it < 64; it++) {
        int p  = blockIdx.x * 256 + wave * 64 + it;
        int bb = p >> 9;
        int t  = p & 511;
        s_lds[wave][l]      = sf[((size_t)t * B_ + bb) * 64 + l];
        s_lds[wave][64 + l] = sb[((size_t)t * B_ + bb) * 64 + l];
        float acc = bp_l[l];
#pragma unroll 8
        for (int d = 0; d < 128; d++)
            acc = fmaf(s_lds[wave][d], wp_t[l * 129 + d], acc);
        float v = tanhf_(acc) * ws_l[l];
        v = wave_sum(v);
        if (l == 0) logits[(size_t)bb * T_ + t] = v + bs[0];
    }
}

__global__ __launch_bounds__(256) void softmax_k(float* __restrict__ logits)
{
    __shared__ float red[8];
    const int b = blockIdx.x, tid = threadIdx.x;
    const int wave = tid >> 6, l = tid & 63;
    float* row = logits + (size_t)b * T_;
    float l0 = row[tid], l1 = row[tid + 256];
    float m = wave_max(fmaxf(l0, l1));
    if (l == 0) red[wave] = m;
    __syncthreads();
    m = fmaxf(fmaxf(red[0], red[1]), fmaxf(red[2], red[3]));
    float e0 = __expf(l0 - m), e1 = __expf(l1 - m);
    float s = wave_sum(e0 + e1);
    if (l == 0) red[4 + wave] = s;
    __syncthreads();
    s = red[4] + red[5] + red[6] + red[7];
    row[tid]       = e0 / s;
    row[tid + 256] = e1 / s;
}

__global__ __launch_bounds__(128) void ctx_k(
    const float* __restrict__ wsm, const float* __restrict__ sf,
    const float* __restrict__ sb, const float* __restrict__ stW,
    const float* __restrict__ stb, float* __restrict__ ctxo)
{
    __shared__ float wrow[512];
    __shared__ float cpre[128];
    const int b = blockIdx.x, tid = threadIdx.x;
#pragma unroll
    for (int i = 0; i < 4; i++) wrow[i * 128 + tid] = wsm[(size_t)b * T_ + i * 128 + tid];
    __syncthreads();
    const float* src = (tid < 64) ? sf : sb;
    const int d = tid & 63;
    float acc = 0.0f;
#pragma unroll 4
    for (int t = 0; t < 512; t++)
        acc = fmaf(wrow[t], src[((size_t)t * B_ + b) * 64 + d], acc);
    cpre[tid] = acc;
    __syncthreads();
    float a2 = stb[tid];
#pragma unroll 8
    for (int i2 = 0; i2 < 128; i2++)
        a2 = fmaf(cpre[i2], stW[(size_t)i2 * 128 + tid], a2);
    ctxo[(size_t)b * 128 + tid] = a2;
}

__global__ __launch_bounds__(128) void tail2(
    const float* __restrict__ fastl, const float* __restrict__ ctxo,
    const float* __restrict__ gW1, const float* __restrict__ gb1,
    const float* __restrict__ gW2, const float* __restrict__ gb2,
    const float* __restrict__ hW1, const float* __restrict__ hb1,
    const float* __restrict__ hW2, const float* __restrict__ hb2,
    float* __restrict__ outp)
{
    __shared__ float gin[256];
    __shared__ float outv[384];
    __shared__ float red2[2];
    const int b = blockIdx.x, tid = threadIdx.x;
    gin[tid]       = fastl[(size_t)b * 128 + tid];
    gin[128 + tid] = ctxo[(size_t)b * 128 + tid];
    __syncthreads();
    float a = gb1[tid];
#pragma unroll 8
    for (int i = 0; i < 256; i++)
        a = fmaf(gin[i], gW1[(size_t)i * 128 + tid], a);
    float gh = fmaxf(a, 0.0f);
    float v = wave_sum(gh * gW2[tid]);
    if ((tid & 63) == 0) red2[tid >> 6] = v;
    __syncthreads();
    float gate = sigmoidf_(red2[0] + red2[1] + gb2[0]);
    float fl = gin[tid], sc = gin[128 + tid];
    outv[tid]       = gate * fl + (1.0f - gate) * sc;
    outv[128 + tid] = fl;
    outv[256 + tid] = sc;
    __syncthreads();
    float a1 = hb1[tid];
#pragma unroll 8
    for (int i = 0; i < 384; i++)
        a1 = fmaf(outv[i], hW1[(size_t)i * 128 + tid], a1);
    float h1v = fmaxf(a1, 0.0f);
    float vv = wave_sum(h1v * hW2[tid]);
    if ((tid & 63) == 0) red2[tid >> 6] = vv;
    __syncthreads();
    if (tid == 0) outp[b] = red2[0] + red2[1] + hb2[0];
}

extern "C" void kernel_launch(void* const* d_in, const int* in_sizes, int n_in,
                              void* d_out, int out_size, void* d_ws, size_t ws_size,
                              hipStream_t stream)
{
    (void)in_sizes; (void)n_in; (void)out_size;
    const float* x      = (const float*)d_in[0];
    const float* gfWi   = (const float*)d_in[1];
    const float* gfWh   = (const float*)d_in[2];
    const float* gfbi   = (const float*)d_in[3];
    const float* gfbh   = (const float*)d_in[4];
    const float* gbWi   = (const float*)d_in[5];
    const float* gbbi   = (const float*)d_in[7];
    const float* gbbh   = (const float*)d_in[8];
    const float* hbfW   = (const float*)d_in[9];
    const float* hbfb   = (const float*)d_in[10];
    const float* hbfU   = (const float*)d_in[11];
    const float* hbfc   = (const float*)d_in[12];
    const float* hbbW   = (const float*)d_in[13];
    const float* hbbb   = (const float*)d_in[14];
    const float* hbbU   = (const float*)d_in[15];
    const float* hbbc   = (const float*)d_in[16];
    const float* fastW  = (const float*)d_in[17];
    const float* fastb  = (const float*)d_in[18];
    const float* stabW  = (const float*)d_in[19];
    const float* stabb  = (const float*)d_in[20];
    const float* attnpW = (const float*)d_in[21];
    const float* attnpb = (const float*)d_in[22];
    const float* attnsW = (const float*)d_in[23];
    const float* attnsb = (const float*)d_in[24];
    const float* gW1    = (const float*)d_in[25];
    const float* gb1    = (const float*)d_in[26];
    const float* gW2    = (const float*)d_in[27];
    const float* gb2    = (const float*)d_in[28];
    const float* hW1    = (const float*)d_in[29];
    const float* hb1    = (const float*)d_in[30];
    const float* hW2    = (const float*)d_in[31];
    const float* hb2    = (const float*)d_in[32];

    float* ws    = (float*)d_ws;
    float* sf    = ws + F_SF;
    float* sb    = ws + F_SB;
    float* st    = ws + F_ST;
    float* fastl = ws + F_FASTL;
    float* logit = ws + F_LOG;
    float* ctxo  = ws + F_CTX;

    const size_t wsf = ws_size / sizeof(float);
    int C = T_;
    while (C > 1 && F_CHUNK + (size_t)C * B_ * 832 > wsf) C >>= 1;
    const int nc = T_ / C;

    float* xg_c  = ws + F_CHUNK;
    float* xpf_c = xg_c  + (size_t)C * B_ * 192;
    float* xpb_c = xpf_c + (size_t)C * B_ * 320;

    for (int c = 0; c < nc; c++) {
        const int t0 = c * C;
        gemm_in<192, true,  false><<<dim3(3, 2, C), 256, 0, stream>>>(x, gfWi, gfbi, nullptr, xg_c, t0);
        gemm_in<320, false, false><<<dim3(5, 2, C), 256, 0, stream>>>(x, hbfW, hbfb, hbfc, xpf_c, t0);
        gemm_in<320, false, true ><<<dim3(5, 2, C), 256, 0, stream>>>(x, hbbW, hbbb, hbbc, xpb_c, t0);
        recur<<<dim3(256), 384, 0, stream>>>(xg_c, xpf_c, xpb_c, gfWh, gfbh, hbfU, hbbU,
                                             sf, sb, st, t0, C);
    }

    tail1<<<dim3(B_), 64, 0, stream>>>(x, gbWi, gbbi, gbbh, st, fastW, fastb, fastl);

    attn_logits<<<dim3(512), 256, 0, stream>>>(sf, sb, attnpW, attnpb, attnsW, attnsb, logit);
    softmax_k<<<dim3(B_), 256, 0, stream>>>(logit);
    ctx_k<<<dim3(B_), 128, 0, stream>>>(logit, sf, sb, stabW, stabb, ctxo);

    tail2<<<dim3(B_), 128, 0, stream>>>(fastl, ctxo, gW1, gb1, gW2, gb2,
                                        hW1, hb1, hW2, hb2, (float*)d_out);
}